// Round 1
// baseline (461.622 us; speedup 1.0000x reference)
//
#include <hip/hip_runtime.h>
#include <math.h>

// E-Langevin sampler, fully fused: one kernel runs all 5 scan steps.
// Key facts exploited:
//  * rows are independent -> one wave owns one row for the whole scan
//  * x is binary -> x@W is a gather-sum of W rows; x_delta@W is an
//    incremental sparse update (E[~19.5] flipped bits/row/step)
//  * accepted y2 becomes next step's y -> only ONE dense gather (init) total

namespace {

constexpr int kB = 16384;
constexpr int kD = 256;
constexpr int kSteps = 5;

__device__ __forceinline__ float wave_sum(float v) {
#pragma unroll
  for (int off = 32; off > 0; off >>= 1) v += __shfl_xor(v, off, 64);
  return v;
}

__device__ __forceinline__ float sigmoid_f(float t) {
  // numerically stable 1/(1+exp(-t)); precise expf to keep binary
  // flip decisions aligned with the fp32 numpy reference
  if (t >= 0.0f) {
    float e = expf(-t);
    return 1.0f / (1.0f + e);
  } else {
    float e = expf(t);
    return e / (1.0f + e);
  }
}

__global__ __launch_bounds__(256) void els_fused(
    const float* __restrict__ x_in, const float* __restrict__ xa_in,
    const float* __restrict__ W, const float* __restrict__ bvec,
    const float* __restrict__ rr, const float* __restrict__ noise,
    const float* __restrict__ accept_u, float* __restrict__ out) {
  const int lane = threadIdx.x & 63;
  const int row = blockIdx.x * 4 + (threadIdx.x >> 6);  // 4 waves/block
  const int c0 = lane << 2;  // this lane owns columns c0..c0+3

  const float4 x4 = *reinterpret_cast<const float4*>(x_in + (size_t)row * kD + c0);
  const float4 a4 = *reinterpret_cast<const float4*>(xa_in + (size_t)row * kD + c0);
  const float4 b4 = *reinterpret_cast<const float4*>(bvec + c0);
  float xv[4] = {x4.x, x4.y, x4.z, x4.w};
  float xa[4] = {a4.x, a4.y, a4.z, a4.w};
  const float bv[4] = {b4.x, b4.y, b4.z, b4.w};
  float y[4] = {0.0f, 0.0f, 0.0f, 0.0f};

  // ---- init: y = x @ W as a gather of W rows where x[d] == 1 ----
#pragma unroll
  for (int i = 0; i < 4; ++i) {
    unsigned long long m = __ballot(xv[i] > 0.5f);
    while (m) {
      const int j = __builtin_ctzll(m);
      m &= m - 1;
      const int d = 4 * j + i;
      const float4 w = *reinterpret_cast<const float4*>(W + (size_t)d * kD + c0);
      y[0] += w.x;
      y[1] += w.y;
      y[2] += w.z;
      y[3] += w.w;
    }
  }

  for (int step = 0; step < kSteps; ++step) {
    const size_t off = ((size_t)step * kB + row) * kD + c0;
    const float4 r4 = *reinterpret_cast<const float4*>(rr + off);
    const float4 n4 = *reinterpret_cast<const float4*>(noise + off);
    const float rrv[4] = {r4.x, r4.y, r4.z, r4.w};
    const float nzv[4] = {n4.x, n4.y, n4.z, n4.w};
    const float u = accept_u[(size_t)step * kB + row];

    float ga[4], xd[4], xda[4];
    bool ind[4];
    float s_lpf = 0.f, s_xy = 0.f, s_xb = 0.f, s_sqc = 0.f, s_fwd = 0.f;
    unsigned long long fm[4], sm[4];

#pragma unroll
    for (int i = 0; i < 4; ++i) {
      ga[i] = (xv[i] - xa[i]) / 1.0e4f;                 // agrad, ETA=1e4
      const float sgn = 1.0f - 2.0f * xv[i];            // -(2x-1)
      const float gm = (y[i] + bv[i] - ga[i]) * sgn / 2.0f;  // TEMP=2
      const float p = sigmoid_f(gm - 2.5f);             // term2 = 1/(2*0.2)
      ind[i] = rrv[i] < p;
      xd[i] = ind[i] ? 1.0f - xv[i] : xv[i];
      xda[i] = xa[i] + 0.25f * ga[i] + 0.70710678118654752f * nzv[i];
      const float pr = ind[i] ? p : 1.0f - p;
      s_lpf += logf(pr + 1e-10f);
      s_xy += xv[i] * y[i];
      s_xb += xv[i] * bv[i];
      const float dc = xv[i] - xa[i];
      s_sqc += dc * dc;
      const float fw = xda[i] - (xa[i] + 0.25f * ga[i]);
      s_fwd += fw * fw;
      fm[i] = __ballot(ind[i]);
      sm[i] = __ballot(xv[i] > 0.5f);  // sign: flip 1->0 subtracts W row
    }

    // ---- y2 = x_delta @ W via sparse update of y over flipped bits ----
    float y2[4] = {y[0], y[1], y[2], y[3]};
#pragma unroll
    for (int i = 0; i < 4; ++i) {
      unsigned long long m = fm[i];
      while (m) {
        const int j = __builtin_ctzll(m);
        m &= m - 1;
        const int d = 4 * j + i;
        const float s = ((sm[i] >> j) & 1ull) ? -1.0f : 1.0f;
        const float4 w = *reinterpret_cast<const float4*>(W + (size_t)d * kD + c0);
        y2[0] = fmaf(s, w.x, y2[0]);
        y2[1] = fmaf(s, w.y, y2[1]);
        y2[2] = fmaf(s, w.z, y2[2]);
        y2[3] = fmaf(s, w.w, y2[3]);
      }
    }

    float s_lpr = 0.f, s_xdy = 0.f, s_xdb = 0.f, s_sqn = 0.f, s_rev = 0.f;
#pragma unroll
    for (int i = 0; i < 4; ++i) {
      const float ga2 = (xd[i] - xda[i]) / 1.0e4f;
      const float sgn2 = 1.0f - 2.0f * xd[i];
      const float gm2 = (y2[i] + bv[i] - ga2) * sgn2 / 2.0f;
      const float p2 = sigmoid_f(gm2 - 2.5f);
      const float pr2 = ind[i] ? p2 : 1.0f - p2;
      s_lpr += logf(pr2 + 1e-10f);
      s_xdy += xd[i] * y2[i];
      s_xdb += xd[i] * bv[i];
      const float dn = xd[i] - xda[i];
      s_sqn += dn * dn;
      const float rv = xa[i] - (xda[i] + 0.25f * ga2);
      s_rev += rv * rv;
    }

    // row reductions (wave = row)
    s_lpf = wave_sum(s_lpf);
    s_lpr = wave_sum(s_lpr);
    s_xy = wave_sum(s_xy);
    s_xb = wave_sum(s_xb);
    s_xdy = wave_sum(s_xdy);
    s_xdb = wave_sum(s_xdb);
    s_sqc = wave_sum(s_sqc);
    s_sqn = wave_sum(s_sqn);
    s_rev = wave_sum(s_rev);
    s_fwd = wave_sum(s_fwd);

    const float E_cur = 0.5f * s_xy + s_xb;
    const float E_new = 0.5f * s_xdy + s_xdb;
    const float m_term = (E_new - s_sqn / 2.0e4f) - (E_cur - s_sqc / 2.0e4f);
    // add_rev = s_rev / (-2*ALPHA_A) = -s_rev ; add_fwd = -s_fwd
    const float la = m_term - s_rev + s_fwd + s_lpr - s_lpf;
    const bool acc = la > logf(u);

#pragma unroll
    for (int i = 0; i < 4; ++i) {
      xv[i] = acc ? xd[i] : xv[i];
      xa[i] = acc ? xda[i] : xa[i];
      y[i] = acc ? y2[i] : y[i];
    }
  }

  float4 ox = {xv[0], xv[1], xv[2], xv[3]};
  float4 oa = {xa[0], xa[1], xa[2], xa[3]};
  *reinterpret_cast<float4*>(out + (size_t)row * kD + c0) = ox;
  *reinterpret_cast<float4*>(out + (size_t)kB * kD + (size_t)row * kD + c0) = oa;
}

}  // namespace

extern "C" void kernel_launch(void* const* d_in, const int* in_sizes, int n_in,
                              void* d_out, int out_size, void* d_ws, size_t ws_size,
                              hipStream_t stream) {
  const float* x = (const float*)d_in[0];
  const float* xa = (const float*)d_in[1];
  const float* W = (const float*)d_in[2];
  const float* b = (const float*)d_in[3];
  const float* rr = (const float*)d_in[4];
  const float* noise = (const float*)d_in[5];
  const float* au = (const float*)d_in[6];
  float* out = (float*)d_out;

  dim3 grid(kB / 4);
  dim3 block(256);
  hipLaunchKernelGGL(els_fused, grid, block, 0, stream, x, xa, W, b, rr, noise,
                     au, out);
}

// Round 2
// 399.660 us; speedup vs baseline: 1.1550x; 1.1550x over previous
//
#include <hip/hip_runtime.h>
#include <math.h>

// E-Langevin sampler, fully fused: one kernel runs all 5 scan steps.
//  * rows independent -> one wave owns one row for the whole scan
//  * x binary -> x@W is a gather-sum of W rows; x_delta@W is an
//    incremental sparse update (~19.5 flipped bits/row/step)
//  * gathers are 4-wide unrolled (mask is wave-uniform -> scalar loop
//    control) so 4 global_load_dwordx4 are in flight per wave, turning
//    the L2-latency-bound gather into an L2-throughput-bound one.
//  * accumulation order is kept bitwise identical to the serial version
//    (w0..w3 in ascending bit order, i=0..3 sequential) so fp32 rounding
//    -- and therefore every binary flip/accept decision -- is unchanged.

namespace {

constexpr int kB = 16384;
constexpr int kD = 256;
constexpr int kSteps = 5;

__device__ __forceinline__ float wave_sum(float v) {
#pragma unroll
  for (int off = 32; off > 0; off >>= 1) v += __shfl_xor(v, off, 64);
  return v;
}

__device__ __forceinline__ float sigmoid_f(float t) {
  if (t >= 0.0f) {
    float e = expf(-t);
    return 1.0f / (1.0f + e);
  } else {
    float e = expf(t);
    return e / (1.0f + e);
  }
}

__global__ __launch_bounds__(256) void els_fused(
    const float* __restrict__ x_in, const float* __restrict__ xa_in,
    const float* __restrict__ W, const float* __restrict__ bvec,
    const float* __restrict__ rr, const float* __restrict__ noise,
    const float* __restrict__ accept_u, float* __restrict__ out) {
  const int lane = threadIdx.x & 63;
  const int row = blockIdx.x * 4 + (threadIdx.x >> 6);  // 4 waves/block
  const int c0 = lane << 2;  // this lane owns columns c0..c0+3

  const float4 x4 = *reinterpret_cast<const float4*>(x_in + (size_t)row * kD + c0);
  const float4 a4 = *reinterpret_cast<const float4*>(xa_in + (size_t)row * kD + c0);
  const float4 b4 = *reinterpret_cast<const float4*>(bvec + c0);
  float xv[4] = {x4.x, x4.y, x4.z, x4.w};
  float xa[4] = {a4.x, a4.y, a4.z, a4.w};
  const float bv[4] = {b4.x, b4.y, b4.z, b4.w};
  float y[4] = {0.0f, 0.0f, 0.0f, 0.0f};

  // ---- init: y = x @ W, gather of W rows where x[d]==1, 4-wide MLP ----
#pragma unroll
  for (int i = 0; i < 4; ++i) {
    unsigned long long m = __ballot(xv[i] > 0.5f);
    const int cnt = __popcll(m);
    int t = 0;
    for (; t + 4 <= cnt; t += 4) {
      const int j0 = __builtin_ctzll(m); m &= m - 1;
      const int j1 = __builtin_ctzll(m); m &= m - 1;
      const int j2 = __builtin_ctzll(m); m &= m - 1;
      const int j3 = __builtin_ctzll(m); m &= m - 1;
      const float4 w0 = *reinterpret_cast<const float4*>(W + (size_t)(4 * j0 + i) * kD + c0);
      const float4 w1 = *reinterpret_cast<const float4*>(W + (size_t)(4 * j1 + i) * kD + c0);
      const float4 w2 = *reinterpret_cast<const float4*>(W + (size_t)(4 * j2 + i) * kD + c0);
      const float4 w3 = *reinterpret_cast<const float4*>(W + (size_t)(4 * j3 + i) * kD + c0);
      y[0] += w0.x; y[1] += w0.y; y[2] += w0.z; y[3] += w0.w;
      y[0] += w1.x; y[1] += w1.y; y[2] += w1.z; y[3] += w1.w;
      y[0] += w2.x; y[1] += w2.y; y[2] += w2.z; y[3] += w2.w;
      y[0] += w3.x; y[1] += w3.y; y[2] += w3.z; y[3] += w3.w;
    }
    for (; t < cnt; ++t) {
      const int j = __builtin_ctzll(m); m &= m - 1;
      const float4 w = *reinterpret_cast<const float4*>(W + (size_t)(4 * j + i) * kD + c0);
      y[0] += w.x; y[1] += w.y; y[2] += w.z; y[3] += w.w;
    }
  }

  for (int step = 0; step < kSteps; ++step) {
    const size_t off = ((size_t)step * kB + row) * kD + c0;
    const float4 r4 = *reinterpret_cast<const float4*>(rr + off);
    const float4 n4 = *reinterpret_cast<const float4*>(noise + off);
    const float rrv[4] = {r4.x, r4.y, r4.z, r4.w};
    const float nzv[4] = {n4.x, n4.y, n4.z, n4.w};
    const float u = accept_u[(size_t)step * kB + row];

    float ga[4], xd[4], xda[4];
    bool ind[4];
    float s_lpf = 0.f, s_xy = 0.f, s_xb = 0.f, s_sqc = 0.f, s_fwd = 0.f;
    unsigned long long fm[4], sm[4];

#pragma unroll
    for (int i = 0; i < 4; ++i) {
      ga[i] = (xv[i] - xa[i]) / 1.0e4f;                 // agrad, ETA=1e4
      const float sgn = 1.0f - 2.0f * xv[i];            // -(2x-1)
      const float gm = (y[i] + bv[i] - ga[i]) * sgn / 2.0f;  // TEMP=2
      const float p = sigmoid_f(gm - 2.5f);             // term2 = 1/(2*0.2)
      ind[i] = rrv[i] < p;
      xd[i] = ind[i] ? 1.0f - xv[i] : xv[i];
      xda[i] = xa[i] + 0.25f * ga[i] + 0.70710678118654752f * nzv[i];
      const float pr = ind[i] ? p : 1.0f - p;
      s_lpf += logf(pr + 1e-10f);
      s_xy += xv[i] * y[i];
      s_xb += xv[i] * bv[i];
      const float dc = xv[i] - xa[i];
      s_sqc += dc * dc;
      const float fw = xda[i] - (xa[i] + 0.25f * ga[i]);
      s_fwd += fw * fw;
      fm[i] = __ballot(ind[i]);
      sm[i] = __ballot(xv[i] > 0.5f);  // flip 1->0 subtracts the W row
    }

    // ---- y2 = x_delta @ W via sparse update over flipped bits, 4-wide ----
    float y2[4] = {y[0], y[1], y[2], y[3]};
#pragma unroll
    for (int i = 0; i < 4; ++i) {
      unsigned long long m = fm[i];
      const int cnt = __popcll(m);
      int t = 0;
      for (; t + 4 <= cnt; t += 4) {
        const int j0 = __builtin_ctzll(m); m &= m - 1;
        const int j1 = __builtin_ctzll(m); m &= m - 1;
        const int j2 = __builtin_ctzll(m); m &= m - 1;
        const int j3 = __builtin_ctzll(m); m &= m - 1;
        const float s0 = ((sm[i] >> j0) & 1ull) ? -1.0f : 1.0f;
        const float s1 = ((sm[i] >> j1) & 1ull) ? -1.0f : 1.0f;
        const float s2 = ((sm[i] >> j2) & 1ull) ? -1.0f : 1.0f;
        const float s3 = ((sm[i] >> j3) & 1ull) ? -1.0f : 1.0f;
        const float4 w0 = *reinterpret_cast<const float4*>(W + (size_t)(4 * j0 + i) * kD + c0);
        const float4 w1 = *reinterpret_cast<const float4*>(W + (size_t)(4 * j1 + i) * kD + c0);
        const float4 w2 = *reinterpret_cast<const float4*>(W + (size_t)(4 * j2 + i) * kD + c0);
        const float4 w3 = *reinterpret_cast<const float4*>(W + (size_t)(4 * j3 + i) * kD + c0);
        y2[0] = fmaf(s0, w0.x, y2[0]); y2[1] = fmaf(s0, w0.y, y2[1]);
        y2[2] = fmaf(s0, w0.z, y2[2]); y2[3] = fmaf(s0, w0.w, y2[3]);
        y2[0] = fmaf(s1, w1.x, y2[0]); y2[1] = fmaf(s1, w1.y, y2[1]);
        y2[2] = fmaf(s1, w1.z, y2[2]); y2[3] = fmaf(s1, w1.w, y2[3]);
        y2[0] = fmaf(s2, w2.x, y2[0]); y2[1] = fmaf(s2, w2.y, y2[1]);
        y2[2] = fmaf(s2, w2.z, y2[2]); y2[3] = fmaf(s2, w2.w, y2[3]);
        y2[0] = fmaf(s3, w3.x, y2[0]); y2[1] = fmaf(s3, w3.y, y2[1]);
        y2[2] = fmaf(s3, w3.z, y2[2]); y2[3] = fmaf(s3, w3.w, y2[3]);
      }
      for (; t < cnt; ++t) {
        const int j = __builtin_ctzll(m); m &= m - 1;
        const float s = ((sm[i] >> j) & 1ull) ? -1.0f : 1.0f;
        const float4 w = *reinterpret_cast<const float4*>(W + (size_t)(4 * j + i) * kD + c0);
        y2[0] = fmaf(s, w.x, y2[0]); y2[1] = fmaf(s, w.y, y2[1]);
        y2[2] = fmaf(s, w.z, y2[2]); y2[3] = fmaf(s, w.w, y2[3]);
      }
    }

    float s_lpr = 0.f, s_xdy = 0.f, s_xdb = 0.f, s_sqn = 0.f, s_rev = 0.f;
#pragma unroll
    for (int i = 0; i < 4; ++i) {
      const float ga2 = (xd[i] - xda[i]) / 1.0e4f;
      const float sgn2 = 1.0f - 2.0f * xd[i];
      const float gm2 = (y2[i] + bv[i] - ga2) * sgn2 / 2.0f;
      const float p2 = sigmoid_f(gm2 - 2.5f);
      const float pr2 = ind[i] ? p2 : 1.0f - p2;
      s_lpr += logf(pr2 + 1e-10f);
      s_xdy += xd[i] * y2[i];
      s_xdb += xd[i] * bv[i];
      const float dn = xd[i] - xda[i];
      s_sqn += dn * dn;
      const float rv = xa[i] - (xda[i] + 0.25f * ga2);
      s_rev += rv * rv;
    }

    // row reductions (wave = row)
    s_lpf = wave_sum(s_lpf);
    s_lpr = wave_sum(s_lpr);
    s_xy = wave_sum(s_xy);
    s_xb = wave_sum(s_xb);
    s_xdy = wave_sum(s_xdy);
    s_xdb = wave_sum(s_xdb);
    s_sqc = wave_sum(s_sqc);
    s_sqn = wave_sum(s_sqn);
    s_rev = wave_sum(s_rev);
    s_fwd = wave_sum(s_fwd);

    const float E_cur = 0.5f * s_xy + s_xb;
    const float E_new = 0.5f * s_xdy + s_xdb;
    const float m_term = (E_new - s_sqn / 2.0e4f) - (E_cur - s_sqc / 2.0e4f);
    // add_rev = s_rev / (-2*ALPHA_A) = -s_rev ; add_fwd = -s_fwd
    const float la = m_term - s_rev + s_fwd + s_lpr - s_lpf;
    const bool acc = la > logf(u);

#pragma unroll
    for (int i = 0; i < 4; ++i) {
      xv[i] = acc ? xd[i] : xv[i];
      xa[i] = acc ? xda[i] : xa[i];
      y[i] = acc ? y2[i] : y[i];
    }
  }

  float4 ox = {xv[0], xv[1], xv[2], xv[3]};
  float4 oa = {xa[0], xa[1], xa[2], xa[3]};
  *reinterpret_cast<float4*>(out + (size_t)row * kD + c0) = ox;
  *reinterpret_cast<float4*>(out + (size_t)kB * kD + (size_t)row * kD + c0) = oa;
}

}  // namespace

extern "C" void kernel_launch(void* const* d_in, const int* in_sizes, int n_in,
                              void* d_out, int out_size, void* d_ws, size_t ws_size,
                              hipStream_t stream) {
  const float* x = (const float*)d_in[0];
  const float* xa = (const float*)d_in[1];
  const float* W = (const float*)d_in[2];
  const float* b = (const float*)d_in[3];
  const float* rr = (const float*)d_in[4];
  const float* noise = (const float*)d_in[5];
  const float* au = (const float*)d_in[6];
  float* out = (float*)d_out;

  dim3 grid(kB / 4);
  dim3 block(256);
  hipLaunchKernelGGL(els_fused, grid, block, 0, stream, x, xa, W, b, rr, noise,
                     au, out);
}

// Round 3
// 387.743 us; speedup vs baseline: 1.1905x; 1.0307x over previous
//
#include <hip/hip_runtime.h>
#include <math.h>

// E-Langevin sampler, fully fused: one kernel runs all 5 scan steps.
//  * rows independent -> one wave owns one row for the whole scan
//  * x binary -> x@W is a gather-sum of W rows; x_delta@W is an
//    incremental sparse update (~19.5 flipped bits/row/step)
//  * gathers 8-wide unrolled (mask is wave-uniform -> scalar loop control)
//    so 8 global_load_dwordx4 are in flight per wave
//  * next step's rr/noise/accept_u prefetched one iteration ahead so the
//    ~900-cycle cold-HBM latency overlaps the current step's compute
//  * ALL float arithmetic and accumulation order kept bitwise identical to
//    the passing round-1/2 kernel (ascending bit order in gathers, same
//    wave_sum butterfly, same formulas) -- absmax must stay 0.

namespace {

constexpr int kB = 16384;
constexpr int kD = 256;
constexpr int kSteps = 5;

__device__ __forceinline__ float wave_sum(float v) {
#pragma unroll
  for (int off = 32; off > 0; off >>= 1) v += __shfl_xor(v, off, 64);
  return v;
}

__device__ __forceinline__ float sigmoid_f(float t) {
  if (t >= 0.0f) {
    float e = expf(-t);
    return 1.0f / (1.0f + e);
  } else {
    float e = expf(t);
    return e / (1.0f + e);
  }
}

__global__ __launch_bounds__(256) void els_fused(
    const float* __restrict__ x_in, const float* __restrict__ xa_in,
    const float* __restrict__ W, const float* __restrict__ bvec,
    const float* __restrict__ rr, const float* __restrict__ noise,
    const float* __restrict__ accept_u, float* __restrict__ out) {
  const int lane = threadIdx.x & 63;
  const int row = blockIdx.x * 4 + (threadIdx.x >> 6);  // 4 waves/block
  const int c0 = lane << 2;  // this lane owns columns c0..c0+3

  const float4 x4 = *reinterpret_cast<const float4*>(x_in + (size_t)row * kD + c0);
  const float4 a4 = *reinterpret_cast<const float4*>(xa_in + (size_t)row * kD + c0);
  const float4 b4 = *reinterpret_cast<const float4*>(bvec + c0);
  float xv[4] = {x4.x, x4.y, x4.z, x4.w};
  float xa[4] = {a4.x, a4.y, a4.z, a4.w};
  const float bv[4] = {b4.x, b4.y, b4.z, b4.w};
  float y[4] = {0.0f, 0.0f, 0.0f, 0.0f};

  // prefetch step 0 inputs (consumed below; long latency hidden by init gather)
  float4 r4 = *reinterpret_cast<const float4*>(rr + (size_t)row * kD + c0);
  float4 n4 = *reinterpret_cast<const float4*>(noise + (size_t)row * kD + c0);
  float u = accept_u[row];

  // ---- init: y = x @ W, gather of W rows where x[d]==1, 8-wide MLP ----
#pragma unroll
  for (int i = 0; i < 4; ++i) {
    unsigned long long m = __ballot(xv[i] > 0.5f);
    const int cnt = __popcll(m);
    int t = 0;
    for (; t + 8 <= cnt; t += 8) {
      int j[8];
#pragma unroll
      for (int q = 0; q < 8; ++q) { j[q] = __builtin_ctzll(m); m &= m - 1; }
      float4 w[8];
#pragma unroll
      for (int q = 0; q < 8; ++q)
        w[q] = *reinterpret_cast<const float4*>(W + (size_t)(4 * j[q] + i) * kD + c0);
#pragma unroll
      for (int q = 0; q < 8; ++q) {
        y[0] += w[q].x; y[1] += w[q].y; y[2] += w[q].z; y[3] += w[q].w;
      }
    }
    for (; t + 4 <= cnt; t += 4) {
      int j[4];
#pragma unroll
      for (int q = 0; q < 4; ++q) { j[q] = __builtin_ctzll(m); m &= m - 1; }
      float4 w[4];
#pragma unroll
      for (int q = 0; q < 4; ++q)
        w[q] = *reinterpret_cast<const float4*>(W + (size_t)(4 * j[q] + i) * kD + c0);
#pragma unroll
      for (int q = 0; q < 4; ++q) {
        y[0] += w[q].x; y[1] += w[q].y; y[2] += w[q].z; y[3] += w[q].w;
      }
    }
    for (; t < cnt; ++t) {
      const int jj = __builtin_ctzll(m); m &= m - 1;
      const float4 w = *reinterpret_cast<const float4*>(W + (size_t)(4 * jj + i) * kD + c0);
      y[0] += w.x; y[1] += w.y; y[2] += w.z; y[3] += w.w;
    }
  }

  for (int step = 0; step < kSteps; ++step) {
    // consume this step's prefetched inputs
    const float rrv[4] = {r4.x, r4.y, r4.z, r4.w};
    const float nzv[4] = {n4.x, n4.y, n4.z, n4.w};
    const float ucur = u;

    // prefetch NEXT step's inputs (issued now, consumed next iteration)
    const int sn = (step + 1 < kSteps) ? step + 1 : step;
    const size_t offn = ((size_t)sn * kB + row) * kD + c0;
    r4 = *reinterpret_cast<const float4*>(rr + offn);
    n4 = *reinterpret_cast<const float4*>(noise + offn);
    u = accept_u[(size_t)sn * kB + row];

    float ga[4], xd[4], xda[4];
    bool ind[4];
    float s_lpf = 0.f, s_xy = 0.f, s_xb = 0.f, s_sqc = 0.f, s_fwd = 0.f;
    unsigned long long fm[4], sm[4];

#pragma unroll
    for (int i = 0; i < 4; ++i) {
      ga[i] = (xv[i] - xa[i]) / 1.0e4f;                 // agrad, ETA=1e4
      const float sgn = 1.0f - 2.0f * xv[i];            // -(2x-1)
      const float gm = (y[i] + bv[i] - ga[i]) * sgn / 2.0f;  // TEMP=2
      const float p = sigmoid_f(gm - 2.5f);             // term2 = 1/(2*0.2)
      ind[i] = rrv[i] < p;
      xd[i] = ind[i] ? 1.0f - xv[i] : xv[i];
      xda[i] = xa[i] + 0.25f * ga[i] + 0.70710678118654752f * nzv[i];
      const float pr = ind[i] ? p : 1.0f - p;
      s_lpf += logf(pr + 1e-10f);
      s_xy += xv[i] * y[i];
      s_xb += xv[i] * bv[i];
      const float dc = xv[i] - xa[i];
      s_sqc += dc * dc;
      const float fw = xda[i] - (xa[i] + 0.25f * ga[i]);
      s_fwd += fw * fw;
      fm[i] = __ballot(ind[i]);
      sm[i] = __ballot(xv[i] > 0.5f);  // flip 1->0 subtracts the W row
    }

    // ---- y2 = x_delta @ W via sparse update over flipped bits, 8-wide ----
    float y2[4] = {y[0], y[1], y[2], y[3]};
#pragma unroll
    for (int i = 0; i < 4; ++i) {
      unsigned long long m = fm[i];
      const int cnt = __popcll(m);
      int t = 0;
      for (; t + 8 <= cnt; t += 8) {
        int j[8];
#pragma unroll
        for (int q = 0; q < 8; ++q) { j[q] = __builtin_ctzll(m); m &= m - 1; }
        float4 w[8];
        float s[8];
#pragma unroll
        for (int q = 0; q < 8; ++q) {
          s[q] = ((sm[i] >> j[q]) & 1ull) ? -1.0f : 1.0f;
          w[q] = *reinterpret_cast<const float4*>(W + (size_t)(4 * j[q] + i) * kD + c0);
        }
#pragma unroll
        for (int q = 0; q < 8; ++q) {
          y2[0] = fmaf(s[q], w[q].x, y2[0]); y2[1] = fmaf(s[q], w[q].y, y2[1]);
          y2[2] = fmaf(s[q], w[q].z, y2[2]); y2[3] = fmaf(s[q], w[q].w, y2[3]);
        }
      }
      for (; t + 4 <= cnt; t += 4) {
        int j[4];
#pragma unroll
        for (int q = 0; q < 4; ++q) { j[q] = __builtin_ctzll(m); m &= m - 1; }
        float4 w[4];
        float s[4];
#pragma unroll
        for (int q = 0; q < 4; ++q) {
          s[q] = ((sm[i] >> j[q]) & 1ull) ? -1.0f : 1.0f;
          w[q] = *reinterpret_cast<const float4*>(W + (size_t)(4 * j[q] + i) * kD + c0);
        }
#pragma unroll
        for (int q = 0; q < 4; ++q) {
          y2[0] = fmaf(s[q], w[q].x, y2[0]); y2[1] = fmaf(s[q], w[q].y, y2[1]);
          y2[2] = fmaf(s[q], w[q].z, y2[2]); y2[3] = fmaf(s[q], w[q].w, y2[3]);
        }
      }
      for (; t < cnt; ++t) {
        const int jj = __builtin_ctzll(m); m &= m - 1;
        const float s = ((sm[i] >> jj) & 1ull) ? -1.0f : 1.0f;
        const float4 w = *reinterpret_cast<const float4*>(W + (size_t)(4 * jj + i) * kD + c0);
        y2[0] = fmaf(s, w.x, y2[0]); y2[1] = fmaf(s, w.y, y2[1]);
        y2[2] = fmaf(s, w.z, y2[2]); y2[3] = fmaf(s, w.w, y2[3]);
      }
    }

    float s_lpr = 0.f, s_xdy = 0.f, s_xdb = 0.f, s_sqn = 0.f, s_rev = 0.f;
#pragma unroll
    for (int i = 0; i < 4; ++i) {
      const float ga2 = (xd[i] - xda[i]) / 1.0e4f;
      const float sgn2 = 1.0f - 2.0f * xd[i];
      const float gm2 = (y2[i] + bv[i] - ga2) * sgn2 / 2.0f;
      const float p2 = sigmoid_f(gm2 - 2.5f);
      const float pr2 = ind[i] ? p2 : 1.0f - p2;
      s_lpr += logf(pr2 + 1e-10f);
      s_xdy += xd[i] * y2[i];
      s_xdb += xd[i] * bv[i];
      const float dn = xd[i] - xda[i];
      s_sqn += dn * dn;
      const float rv = xa[i] - (xda[i] + 0.25f * ga2);
      s_rev += rv * rv;
    }

    // row reductions (wave = row)
    s_lpf = wave_sum(s_lpf);
    s_lpr = wave_sum(s_lpr);
    s_xy = wave_sum(s_xy);
    s_xb = wave_sum(s_xb);
    s_xdy = wave_sum(s_xdy);
    s_xdb = wave_sum(s_xdb);
    s_sqc = wave_sum(s_sqc);
    s_sqn = wave_sum(s_sqn);
    s_rev = wave_sum(s_rev);
    s_fwd = wave_sum(s_fwd);

    const float E_cur = 0.5f * s_xy + s_xb;
    const float E_new = 0.5f * s_xdy + s_xdb;
    const float m_term = (E_new - s_sqn / 2.0e4f) - (E_cur - s_sqc / 2.0e4f);
    // add_rev = s_rev / (-2*ALPHA_A) = -s_rev ; add_fwd = -s_fwd
    const float la = m_term - s_rev + s_fwd + s_lpr - s_lpf;
    const bool acc = la > logf(ucur);

#pragma unroll
    for (int i = 0; i < 4; ++i) {
      xv[i] = acc ? xd[i] : xv[i];
      xa[i] = acc ? xda[i] : xa[i];
      y[i] = acc ? y2[i] : y[i];
    }
  }

  float4 ox = {xv[0], xv[1], xv[2], xv[3]};
  float4 oa = {xa[0], xa[1], xa[2], xa[3]};
  *reinterpret_cast<float4*>(out + (size_t)row * kD + c0) = ox;
  *reinterpret_cast<float4*>(out + (size_t)kB * kD + (size_t)row * kD + c0) = oa;
}

}  // namespace

extern "C" void kernel_launch(void* const* d_in, const int* in_sizes, int n_in,
                              void* d_out, int out_size, void* d_ws, size_t ws_size,
                              hipStream_t stream) {
  const float* x = (const float*)d_in[0];
  const float* xa = (const float*)d_in[1];
  const float* W = (const float*)d_in[2];
  const float* b = (const float*)d_in[3];
  const float* rr = (const float*)d_in[4];
  const float* noise = (const float*)d_in[5];
  const float* au = (const float*)d_in[6];
  float* out = (float*)d_out;

  dim3 grid(kB / 4);
  dim3 block(256);
  hipLaunchKernelGGL(els_fused, grid, block, 0, stream, x, xa, W, b, rr, noise,
                     au, out);
}

// Round 5
// 382.384 us; speedup vs baseline: 1.2072x; 1.0140x over previous
//
#include <hip/hip_runtime.h>
#include <math.h>

// E-Langevin sampler, fully fused: one kernel runs all 5 scan steps.
//  * rows independent -> one wave owns one row for the whole scan
//  * x binary -> x@W is a gather-sum of W rows; x_delta@W is an
//    incremental sparse update (~19.5 flipped bits/row/step)
//  * gather accumulates packed as 2xfp32 (v_pk_add_f32 / v_pk_fma_f32):
//    identical rounding to scalar add/fmaf, half the VALU instructions
//  * rr/noise/x/xa loads and out stores are non-temporal (via native
//    clang vector type -- HIP float4 is rejected by the builtin) so the
//    ~200MB streaming traffic does not evict W (256KB) from the XCD L2s
//  * accumulation order strictly ascending bit order per i-group --
//    bitwise identical to the passing rounds 1-3 (absmax must stay 0)

namespace {

constexpr int kB = 16384;
constexpr int kD = 256;
constexpr int kSteps = 5;

typedef float v2f __attribute__((ext_vector_type(2)));
typedef float v4f __attribute__((ext_vector_type(4)));

__device__ __forceinline__ v4f nt_load4(const float* p) {
  return __builtin_nontemporal_load(reinterpret_cast<const v4f*>(p));
}
__device__ __forceinline__ void nt_store4(float* p, v4f v) {
  __builtin_nontemporal_store(v, reinterpret_cast<v4f*>(p));
}

__device__ __forceinline__ float wave_sum(float v) {
#pragma unroll
  for (int off = 32; off > 0; off >>= 1) v += __shfl_xor(v, off, 64);
  return v;
}

__device__ __forceinline__ float sigmoid_f(float t) {
  if (t >= 0.0f) {
    float e = expf(-t);
    return 1.0f / (1.0f + e);
  } else {
    float e = expf(t);
    return e / (1.0f + e);
  }
}

__global__ __launch_bounds__(256) void els_fused(
    const float* __restrict__ x_in, const float* __restrict__ xa_in,
    const float* __restrict__ W, const float* __restrict__ bvec,
    const float* __restrict__ rr, const float* __restrict__ noise,
    const float* __restrict__ accept_u, float* __restrict__ out) {
  const int lane = threadIdx.x & 63;
  const int row = blockIdx.x * 4 + (threadIdx.x >> 6);  // 4 waves/block
  const int c0 = lane << 2;  // this lane owns columns c0..c0+3

  const v4f x4 = nt_load4(x_in + (size_t)row * kD + c0);
  const v4f a4 = nt_load4(xa_in + (size_t)row * kD + c0);
  const float4 b4 = *reinterpret_cast<const float4*>(bvec + c0);
  float xv[4] = {x4.x, x4.y, x4.z, x4.w};
  float xa[4] = {a4.x, a4.y, a4.z, a4.w};
  const float bv[4] = {b4.x, b4.y, b4.z, b4.w};
  v2f y01 = {0.0f, 0.0f}, y23 = {0.0f, 0.0f};

  // prefetch step 0 inputs (long latency hidden behind the init gather)
  v4f r4 = nt_load4(rr + (size_t)row * kD + c0);
  v4f n4 = nt_load4(noise + (size_t)row * kD + c0);
  float u = accept_u[row];

  // ---- init: y = x @ W, gather of W rows where x[d]==1, 8-wide MLP ----
#pragma unroll
  for (int i = 0; i < 4; ++i) {
    unsigned long long m = __ballot(xv[i] > 0.5f);
    const int cnt = __popcll(m);
    int t = 0;
    for (; t + 8 <= cnt; t += 8) {
      int j[8];
#pragma unroll
      for (int q = 0; q < 8; ++q) { j[q] = __builtin_ctzll(m); m &= m - 1; }
      float4 w[8];
#pragma unroll
      for (int q = 0; q < 8; ++q)
        w[q] = *reinterpret_cast<const float4*>(W + (size_t)(4 * j[q] + i) * kD + c0);
#pragma unroll
      for (int q = 0; q < 8; ++q) {
        y01 += (v2f){w[q].x, w[q].y};
        y23 += (v2f){w[q].z, w[q].w};
      }
    }
    for (; t < cnt; ++t) {
      const int jj = __builtin_ctzll(m); m &= m - 1;
      const float4 w = *reinterpret_cast<const float4*>(W + (size_t)(4 * jj + i) * kD + c0);
      y01 += (v2f){w.x, w.y};
      y23 += (v2f){w.z, w.w};
    }
  }

  for (int step = 0; step < kSteps; ++step) {
    // consume this step's prefetched inputs
    const float rrv[4] = {r4.x, r4.y, r4.z, r4.w};
    const float nzv[4] = {n4.x, n4.y, n4.z, n4.w};
    const float ucur = u;

    // prefetch NEXT step's inputs (issued now, consumed next iteration)
    const int sn = (step + 1 < kSteps) ? step + 1 : step;
    const size_t offn = ((size_t)sn * kB + row) * kD + c0;
    r4 = nt_load4(rr + offn);
    n4 = nt_load4(noise + offn);
    u = accept_u[(size_t)sn * kB + row];

    const float yv[4] = {y01.x, y01.y, y23.x, y23.y};
    float ga[4], xd[4], xda[4];
    bool ind[4];
    float s_lpf = 0.f, s_xy = 0.f, s_xb = 0.f, s_sqc = 0.f, s_fwd = 0.f;
    unsigned long long fm[4], sm[4];

#pragma unroll
    for (int i = 0; i < 4; ++i) {
      ga[i] = (xv[i] - xa[i]) / 1.0e4f;                 // agrad, ETA=1e4
      const float sgn = 1.0f - 2.0f * xv[i];            // -(2x-1)
      const float gm = (yv[i] + bv[i] - ga[i]) * sgn / 2.0f;  // TEMP=2
      const float p = sigmoid_f(gm - 2.5f);             // term2 = 1/(2*0.2)
      ind[i] = rrv[i] < p;
      xd[i] = ind[i] ? 1.0f - xv[i] : xv[i];
      xda[i] = xa[i] + 0.25f * ga[i] + 0.70710678118654752f * nzv[i];
      const float pr = ind[i] ? p : 1.0f - p;
      s_lpf += logf(pr + 1e-10f);
      s_xy += xv[i] * yv[i];
      s_xb += xv[i] * bv[i];
      const float dc = xv[i] - xa[i];
      s_sqc += dc * dc;
      const float fw = xda[i] - (xa[i] + 0.25f * ga[i]);
      s_fwd += fw * fw;
      fm[i] = __ballot(ind[i]);
      sm[i] = __ballot(xv[i] > 0.5f);  // flip 1->0 subtracts the W row
    }

    // ---- y2 = x_delta @ W via sparse update over flipped bits, 4-wide ----
    v2f y2lo = y01, y2hi = y23;
#pragma unroll
    for (int i = 0; i < 4; ++i) {
      unsigned long long m = fm[i];
      const int cnt = __popcll(m);
      int t = 0;
      for (; t + 4 <= cnt; t += 4) {
        int j[4];
#pragma unroll
        for (int q = 0; q < 4; ++q) { j[q] = __builtin_ctzll(m); m &= m - 1; }
        float4 w[4];
        float s[4];
#pragma unroll
        for (int q = 0; q < 4; ++q) {
          s[q] = ((sm[i] >> j[q]) & 1ull) ? -1.0f : 1.0f;
          w[q] = *reinterpret_cast<const float4*>(W + (size_t)(4 * j[q] + i) * kD + c0);
        }
#pragma unroll
        for (int q = 0; q < 4; ++q) {
          const v2f sv = {s[q], s[q]};
          y2lo = __builtin_elementwise_fma(sv, (v2f){w[q].x, w[q].y}, y2lo);
          y2hi = __builtin_elementwise_fma(sv, (v2f){w[q].z, w[q].w}, y2hi);
        }
      }
      for (; t < cnt; ++t) {
        const int jj = __builtin_ctzll(m); m &= m - 1;
        const float s = ((sm[i] >> jj) & 1ull) ? -1.0f : 1.0f;
        const float4 w = *reinterpret_cast<const float4*>(W + (size_t)(4 * jj + i) * kD + c0);
        const v2f sv = {s, s};
        y2lo = __builtin_elementwise_fma(sv, (v2f){w.x, w.y}, y2lo);
        y2hi = __builtin_elementwise_fma(sv, (v2f){w.z, w.w}, y2hi);
      }
    }

    const float y2v[4] = {y2lo.x, y2lo.y, y2hi.x, y2hi.y};
    float s_lpr = 0.f, s_xdy = 0.f, s_xdb = 0.f, s_sqn = 0.f, s_rev = 0.f;
#pragma unroll
    for (int i = 0; i < 4; ++i) {
      const float ga2 = (xd[i] - xda[i]) / 1.0e4f;
      const float sgn2 = 1.0f - 2.0f * xd[i];
      const float gm2 = (y2v[i] + bv[i] - ga2) * sgn2 / 2.0f;
      const float p2 = sigmoid_f(gm2 - 2.5f);
      const float pr2 = ind[i] ? p2 : 1.0f - p2;
      s_lpr += logf(pr2 + 1e-10f);
      s_xdy += xd[i] * y2v[i];
      s_xdb += xd[i] * bv[i];
      const float dn = xd[i] - xda[i];
      s_sqn += dn * dn;
      const float rv = xa[i] - (xda[i] + 0.25f * ga2);
      s_rev += rv * rv;
    }

    // row reductions (wave = row)
    s_lpf = wave_sum(s_lpf);
    s_lpr = wave_sum(s_lpr);
    s_xy = wave_sum(s_xy);
    s_xb = wave_sum(s_xb);
    s_xdy = wave_sum(s_xdy);
    s_xdb = wave_sum(s_xdb);
    s_sqc = wave_sum(s_sqc);
    s_sqn = wave_sum(s_sqn);
    s_rev = wave_sum(s_rev);
    s_fwd = wave_sum(s_fwd);

    const float E_cur = 0.5f * s_xy + s_xb;
    const float E_new = 0.5f * s_xdy + s_xdb;
    const float m_term = (E_new - s_sqn / 2.0e4f) - (E_cur - s_sqc / 2.0e4f);
    // add_rev = s_rev / (-2*ALPHA_A) = -s_rev ; add_fwd = -s_fwd
    const float la = m_term - s_rev + s_fwd + s_lpr - s_lpf;
    const bool acc = la > logf(ucur);

#pragma unroll
    for (int i = 0; i < 4; ++i) {
      xv[i] = acc ? xd[i] : xv[i];
      xa[i] = acc ? xda[i] : xa[i];
    }
    y01 = acc ? y2lo : y01;
    y23 = acc ? y2hi : y23;
  }

  const v4f ox = {xv[0], xv[1], xv[2], xv[3]};
  const v4f oa = {xa[0], xa[1], xa[2], xa[3]};
  nt_store4(out + (size_t)row * kD + c0, ox);
  nt_store4(out + (size_t)kB * kD + (size_t)row * kD + c0, oa);
}

}  // namespace

extern "C" void kernel_launch(void* const* d_in, const int* in_sizes, int n_in,
                              void* d_out, int out_size, void* d_ws, size_t ws_size,
                              hipStream_t stream) {
  const float* x = (const float*)d_in[0];
  const float* xa = (const float*)d_in[1];
  const float* W = (const float*)d_in[2];
  const float* b = (const float*)d_in[3];
  const float* rr = (const float*)d_in[4];
  const float* noise = (const float*)d_in[5];
  const float* au = (const float*)d_in[6];
  float* out = (float*)d_out;

  dim3 grid(kB / 4);
  dim3 block(256);
  hipLaunchKernelGGL(els_fused, grid, block, 0, stream, x, xa, W, b, rr, noise,
                     au, out);
}